// Round 3
// baseline (3628.789 us; speedup 1.0000x reference)
//
#include <hip/hip_runtime.h>
#include <hip/hip_bf16.h>
#include <cstdint>
#include <cstddef>

#define D_MODEL 1024
#define N_HEAD 16
#define HEAD_DIM 64
#define BATCH 4
#define SEQ 2048
#define M_ROWS (BATCH * SEQ) // 8192

// ---------- bf16 helpers (raw ushort handling, RNE) ----------
__device__ __forceinline__ unsigned short f2bf(float f) {
    union { uint32_t i; float f; } c;
    c.f = f;
    uint32_t i = c.i;
    uint32_t r = i + 0x7FFFu + ((i >> 16) & 1u); // round-nearest-even
    return (unsigned short)(r >> 16);
}
__device__ __forceinline__ uint32_t pack_bf2(float a, float b) {
    return (uint32_t)f2bf(a) | ((uint32_t)f2bf(b) << 16);
}
__device__ __forceinline__ void bf2x(uint32_t w, float &lo, float &hi) {
    union { uint32_t i; float f; } c0, c1;
    c0.i = w << 16;
    c1.i = w & 0xFFFF0000u;
    lo = c0.f;
    hi = c1.f;
}

struct __align__(16) U4 { uint32_t x, y, z, w; };

__device__ __forceinline__ void unpack8(U4 raw, float *dst) {
    bf2x(raw.x, dst[0], dst[1]);
    bf2x(raw.y, dst[2], dst[3]);
    bf2x(raw.z, dst[4], dst[5]);
    bf2x(raw.w, dst[6], dst[7]);
}

// ---- dtype-polymorphic 8-element loaders (16B-aligned addresses) ----
__device__ __forceinline__ void load8(const float *__restrict__ p, float *d) {
    float4 a = *(const float4 *)p;
    float4 b = *(const float4 *)(p + 4);
    d[0] = a.x; d[1] = a.y; d[2] = a.z; d[3] = a.w;
    d[4] = b.x; d[5] = b.y; d[6] = b.z; d[7] = b.w;
}
__device__ __forceinline__ void load8(const unsigned short *__restrict__ p, float *d) {
    unpack8(*(const U4 *)p, d);
}

// ---- dtype-polymorphic 8-element stores ----
__device__ __forceinline__ void store8(unsigned short *__restrict__ p, const float *s) {
    U4 ov;
    ov.x = pack_bf2(s[0], s[1]);
    ov.y = pack_bf2(s[2], s[3]);
    ov.z = pack_bf2(s[4], s[5]);
    ov.w = pack_bf2(s[6], s[7]);
    *(U4 *)p = ov;
}
__device__ __forceinline__ void store8(float *__restrict__ p, const float *s) {
    *(float4 *)p = make_float4(s[0], s[1], s[2], s[3]);
    *(float4 *)(p + 4) = make_float4(s[4], s[5], s[6], s[7]);
}

__device__ __forceinline__ float readlane_f(float v, int l) {
    int iv = __builtin_amdgcn_readlane(__float_as_int(v), l);
    return __int_as_float(iv);
}

// ---------------------------------------------------------------------------
// GEMM: C[m][n] = sum_k A[m][k]*W[k][n] + bias[n]
// A: [8192][1024] (TA = float or bf16-ushort) row-major
// W: [1024][1024] fp32 row-major; bias: [1024] fp32
// mode 0: write out[((b*16+h)*2048+s)*64+hd]  (per-head layout)
// mode 1: write out[m*1024+n]                  row-major
// Output dtype TO = ushort (bf16) or float.
// 256 threads, 128x128 tile, 8x8 per thread, TK=16.
// ---------------------------------------------------------------------------
#define GT_M 128
#define GT_N 128
#define GT_K 16

template <typename TA, typename TO>
__global__ __launch_bounds__(256, 2)
void gemm_kernel(const TA *__restrict__ A,
                 const float *__restrict__ W,
                 const float *__restrict__ bias,
                 TO *__restrict__ out,
                 int mode)
{
    __shared__ float Ast[GT_K][GT_M + 4]; // transposed: Ast[k][m], stride 132
    __shared__ float Bs[GT_K][GT_N + 4];

    const int t = threadIdx.x;
    const int tx = t & 15;
    const int ty = t >> 4;
    const int m0 = blockIdx.y * GT_M;
    const int n0 = blockIdx.x * GT_N;

    float acc[8][8];
#pragma unroll
    for (int i = 0; i < 8; i++)
#pragma unroll
        for (int j = 0; j < 8; j++) acc[i][j] = 0.f;

    const int ar = t >> 1;  // A row 0..127
    const int ah = t & 1;   // which 8-wide half of the 16 k's
    const int bk = t >> 4;  // B k-row 0..15
    const int bp = t & 15;  // B 8-col segment

    for (int k0 = 0; k0 < D_MODEL; k0 += GT_K) {
        float af[8], bf[8];
        load8(A + (size_t)(m0 + ar) * D_MODEL + k0 + ah * 8, af);
        load8(W + (size_t)(k0 + bk) * D_MODEL + n0 + bp * 8, bf);
#pragma unroll
        for (int i = 0; i < 8; i++) Ast[ah * 8 + i][ar] = af[i];
        *(float4 *)&Bs[bk][bp * 8 + 0] = make_float4(bf[0], bf[1], bf[2], bf[3]);
        *(float4 *)&Bs[bk][bp * 8 + 4] = make_float4(bf[4], bf[5], bf[6], bf[7]);
        __syncthreads();

#pragma unroll
        for (int kk = 0; kk < GT_K; kk++) {
            float a[8], b[8];
            *(float4 *)&a[0] = *(const float4 *)&Ast[kk][ty * 8];
            *(float4 *)&a[4] = *(const float4 *)&Ast[kk][ty * 8 + 4];
            *(float4 *)&b[0] = *(const float4 *)&Bs[kk][tx * 8];
            *(float4 *)&b[4] = *(const float4 *)&Bs[kk][tx * 8 + 4];
#pragma unroll
            for (int i = 0; i < 8; i++)
#pragma unroll
                for (int j = 0; j < 8; j++)
                    acc[i][j] = fmaf(a[i], b[j], acc[i][j]);
        }
        __syncthreads();
    }

    // bias (fp32)
    float bi[8];
    load8(bias + n0 + tx * 8, bi);

    const int ncol0 = n0 + tx * 8;
#pragma unroll
    for (int i = 0; i < 8; i++) {
        const int m = m0 + ty * 8 + i;
        float cv[8];
#pragma unroll
        for (int j = 0; j < 8; j++) cv[j] = acc[i][j] + bi[j];
        size_t idx;
        if (mode == 0) {
            const int b = m >> 11;        // /2048
            const int s = m & 2047;
            const int hh = ncol0 >> 6;    // head
            const int hd = ncol0 & 63;    // dim within head (multiple of 8)
            idx = ((size_t)(b * N_HEAD + hh) * SEQ + s) * HEAD_DIM + hd;
        } else {
            idx = (size_t)m * D_MODEL + ncol0;
        }
        store8(out + idx, cv);
    }
}

// ---------------------------------------------------------------------------
// Flash attention, causal, scale 1/32.
// Q,K,V: bf16 [B,H,S,64]. AO: bf16 [B,S,1024] row-major (col = h*64+d).
// One workgroup (4 waves) per (b, h, 64-query block). Each wave owns 16 queries.
// lane = key for score phase, lane = dim for PV-update phase.
// ---------------------------------------------------------------------------
#define APAD 4
#define ASTRIDE (HEAD_DIM + APAD) // 68 floats

__global__ __launch_bounds__(256, 2)
void attn_kernel(const unsigned short *__restrict__ Qg,
                 const unsigned short *__restrict__ Kg,
                 const unsigned short *__restrict__ Vg,
                 unsigned short *__restrict__ AO)
{
    __shared__ float Qs[64][ASTRIDE];
    __shared__ float Ks[64][ASTRIDE];
    __shared__ float Vs[64][ASTRIDE];

    const int qb = blockIdx.x;  // 0..31
    const int h = blockIdx.y;
    const int b = blockIdx.z;
    const int t = threadIdx.x;
    const int wave = t >> 6;
    const int lane = t & 63;
    const size_t head_off = (size_t)(b * N_HEAD + h) * SEQ * HEAD_DIM;

    // stage Q (64 rows x 64 dims): thread -> (row = t>>2, 16 cols at (t&3)*16)
    {
        const int r = t >> 2;
        const int p = (t & 3) * 16;
        const unsigned short *src = Qg + head_off + (size_t)(qb * 64 + r) * HEAD_DIM + p;
        float f0[8], f1[8];
        load8(src, f0);
        load8(src + 8, f1);
        *(float4 *)&Qs[r][p + 0]  = make_float4(f0[0], f0[1], f0[2], f0[3]);
        *(float4 *)&Qs[r][p + 4]  = make_float4(f0[4], f0[5], f0[6], f0[7]);
        *(float4 *)&Qs[r][p + 8]  = make_float4(f1[0], f1[1], f1[2], f1[3]);
        *(float4 *)&Qs[r][p + 12] = make_float4(f1[4], f1[5], f1[6], f1[7]);
    }

    float m_i[16], l_i[16], o_acc[16];
#pragma unroll
    for (int i = 0; i < 16; i++) {
        m_i[i] = -INFINITY;
        l_i[i] = 0.f;
        o_acc[i] = 0.f;
    }

    const int q_base = qb * 64 + wave * 16; // global row of this wave's query 0

    for (int kb = 0; kb <= qb; ++kb) {
        __syncthreads(); // previous tile fully consumed (also covers Q staging)
        {
            const int r = t >> 2;
            const int p = (t & 3) * 16;
            const unsigned short *ks = Kg + head_off + (size_t)(kb * 64 + r) * HEAD_DIM + p;
            const unsigned short *vs = Vg + head_off + (size_t)(kb * 64 + r) * HEAD_DIM + p;
            float fk0[8], fk1[8], fv0[8], fv1[8];
            load8(ks, fk0);
            load8(ks + 8, fk1);
            load8(vs, fv0);
            load8(vs + 8, fv1);
            *(float4 *)&Ks[r][p + 0]  = make_float4(fk0[0], fk0[1], fk0[2], fk0[3]);
            *(float4 *)&Ks[r][p + 4]  = make_float4(fk0[4], fk0[5], fk0[6], fk0[7]);
            *(float4 *)&Ks[r][p + 8]  = make_float4(fk1[0], fk1[1], fk1[2], fk1[3]);
            *(float4 *)&Ks[r][p + 12] = make_float4(fk1[4], fk1[5], fk1[6], fk1[7]);
            *(float4 *)&Vs[r][p + 0]  = make_float4(fv0[0], fv0[1], fv0[2], fv0[3]);
            *(float4 *)&Vs[r][p + 4]  = make_float4(fv0[4], fv0[5], fv0[6], fv0[7]);
            *(float4 *)&Vs[r][p + 8]  = make_float4(fv1[0], fv1[1], fv1[2], fv1[3]);
            *(float4 *)&Vs[r][p + 12] = make_float4(fv1[4], fv1[5], fv1[6], fv1[7]);
        }
        __syncthreads();

        const bool diag = (kb == qb);
        const int kglob = kb * 64 + lane;

#pragma unroll
        for (int qg = 0; qg < 4; ++qg) {
            // scores for 4 queries, lane = key
            float s[4] = {0.f, 0.f, 0.f, 0.f};
            const int qr = wave * 16 + qg * 4;
#pragma unroll
            for (int d4 = 0; d4 < HEAD_DIM / 4; ++d4) {
                const float4 kv = *(const float4 *)&Ks[lane][d4 * 4];
#pragma unroll
                for (int r = 0; r < 4; r++) {
                    const float4 qv = *(const float4 *)&Qs[qr + r][d4 * 4];
                    s[r] = fmaf(qv.x, kv.x, s[r]);
                    s[r] = fmaf(qv.y, kv.y, s[r]);
                    s[r] = fmaf(qv.z, kv.z, s[r]);
                    s[r] = fmaf(qv.w, kv.w, s[r]);
                }
            }
            float p[4];
#pragma unroll
            for (int r = 0; r < 4; r++) {
                const int qi = qg * 4 + r;
                float sv = s[r] * 0.03125f; // 1/sqrt(1024)
                if (diag && kglob > q_base + qi) sv = -INFINITY;
                float mb = sv;
#pragma unroll
                for (int off = 32; off >= 1; off >>= 1)
                    mb = fmaxf(mb, __shfl_xor(mb, off, 64));
                const float mnew = fmaxf(m_i[qi], mb);
                const float pv = __expf(sv - mnew);
                const float alpha = __expf(m_i[qi] - mnew);
                float ps = pv;
#pragma unroll
                for (int off = 32; off >= 1; off >>= 1)
                    ps += __shfl_xor(ps, off, 64);
                l_i[qi] = l_i[qi] * alpha + ps;
                m_i[qi] = mnew;
                o_acc[qi] *= alpha;
                p[r] = pv;
            }
            // PV update, lane = dim; p broadcast by readlane
#pragma unroll 4
            for (int j = 0; j < 64; ++j) {
                const float vv = Vs[j][lane];
                o_acc[qg * 4 + 0] = fmaf(readlane_f(p[0], j), vv, o_acc[qg * 4 + 0]);
                o_acc[qg * 4 + 1] = fmaf(readlane_f(p[1], j), vv, o_acc[qg * 4 + 1]);
                o_acc[qg * 4 + 2] = fmaf(readlane_f(p[2], j), vv, o_acc[qg * 4 + 2]);
                o_acc[qg * 4 + 3] = fmaf(readlane_f(p[3], j), vv, o_acc[qg * 4 + 3]);
            }
        }
    }

    // epilogue: AO[b][s][h*64 + lane]
#pragma unroll
    for (int qi = 0; qi < 16; ++qi) {
        const int srow = qb * 64 + wave * 16 + qi;
        const float o = o_acc[qi] / l_i[qi];
        const size_t idx = ((size_t)b * SEQ + srow) * D_MODEL + h * HEAD_DIM + lane;
        AO[idx] = f2bf(o);
    }
}

// ---------------------------------------------------------------------------
extern "C" void kernel_launch(void *const *d_in, const int *in_sizes, int n_in,
                              void *d_out, int out_size, void *d_ws, size_t ws_size,
                              hipStream_t stream)
{
    const float *q  = (const float *)d_in[0];
    const float *k  = (const float *)d_in[1];
    const float *v  = (const float *)d_in[2];
    const float *Wq = (const float *)d_in[3];
    const float *bq = (const float *)d_in[4];
    const float *Wk = (const float *)d_in[5];
    const float *bk = (const float *)d_in[6];
    const float *Wv = (const float *)d_in[7];
    const float *bv = (const float *)d_in[8];
    const float *Wo = (const float *)d_in[9];
    const float *bo = (const float *)d_in[10];
    float *out = (float *)d_out; // fp32 output per reference dtype

    // workspace: Q,K,V in [B,H,S,64] bf16 + AO in [B,S,1024] bf16 = 67.1 MB
    const size_t TENS = (size_t)M_ROWS * D_MODEL; // 8388608 elements
    unsigned short *wsq  = (unsigned short *)d_ws;
    unsigned short *wsk  = wsq + TENS;
    unsigned short *wsv  = wsk + TENS;
    unsigned short *wsao = wsv + TENS;

    dim3 gblk(256);
    dim3 ggrid(D_MODEL / GT_N, M_ROWS / GT_M); // (8, 64)

    gemm_kernel<float, unsigned short><<<ggrid, gblk, 0, stream>>>(q, Wq, bq, wsq, 0);
    gemm_kernel<float, unsigned short><<<ggrid, gblk, 0, stream>>>(k, Wk, bk, wsk, 0);
    gemm_kernel<float, unsigned short><<<ggrid, gblk, 0, stream>>>(v, Wv, bv, wsv, 0);

    attn_kernel<<<dim3(SEQ / 64, N_HEAD, BATCH), 256, 0, stream>>>(wsq, wsk, wsv, wsao);

    gemm_kernel<unsigned short, float><<<ggrid, gblk, 0, stream>>>(wsao, Wo, bo, out, 1);
}

// Round 4
// 1214.941 us; speedup vs baseline: 2.9868x; 2.9868x over previous
//
#include <hip/hip_runtime.h>
#include <hip/hip_bf16.h>
#include <cstdint>
#include <cstddef>

#define D_MODEL 1024
#define N_HEAD 16
#define HEAD_DIM 64
#define BATCH 4
#define SEQ 2048
#define M_ROWS (BATCH * SEQ) // 8192

typedef __attribute__((ext_vector_type(8))) short short8v; // 8 bf16 (4 VGPRs)
typedef __attribute__((ext_vector_type(4))) float f32x4;   // MFMA C/D

// ---------- bf16 helpers ----------
__device__ __forceinline__ unsigned short f2bf(float f) {
    union { uint32_t i; float f; } c;
    c.f = f;
    uint32_t i = c.i;
    uint32_t r = i + 0x7FFFu + ((i >> 16) & 1u); // RNE
    return (unsigned short)(r >> 16);
}
__device__ __forceinline__ uint32_t pack_bf2(float a, float b) {
    return (uint32_t)f2bf(a) | ((uint32_t)f2bf(b) << 16);
}
__device__ __forceinline__ void bf2x(uint32_t w, float &lo, float &hi) {
    union { uint32_t i; float f; } c0, c1;
    c0.i = w << 16;
    c1.i = w & 0xFFFF0000u;
    lo = c0.f;
    hi = c1.f;
}

struct __align__(16) U4 { uint32_t x, y, z, w; };

__device__ __forceinline__ void unpack8(U4 raw, float *dst) {
    bf2x(raw.x, dst[0], dst[1]);
    bf2x(raw.y, dst[2], dst[3]);
    bf2x(raw.z, dst[4], dst[5]);
    bf2x(raw.w, dst[6], dst[7]);
}

// ---- dtype-polymorphic 8-element loaders/stores (16B-aligned) ----
__device__ __forceinline__ void load8(const float *__restrict__ p, float *d) {
    float4 a = *(const float4 *)p;
    float4 b = *(const float4 *)(p + 4);
    d[0] = a.x; d[1] = a.y; d[2] = a.z; d[3] = a.w;
    d[4] = b.x; d[5] = b.y; d[6] = b.z; d[7] = b.w;
}
__device__ __forceinline__ void load8(const unsigned short *__restrict__ p, float *d) {
    unpack8(*(const U4 *)p, d);
}
__device__ __forceinline__ void store8(unsigned short *__restrict__ p, const float *s) {
    U4 ov;
    ov.x = pack_bf2(s[0], s[1]);
    ov.y = pack_bf2(s[2], s[3]);
    ov.z = pack_bf2(s[4], s[5]);
    ov.w = pack_bf2(s[6], s[7]);
    *(U4 *)p = ov;
}
__device__ __forceinline__ void store8(float *__restrict__ p, const float *s) {
    *(float4 *)p = make_float4(s[0], s[1], s[2], s[3]);
    *(float4 *)(p + 4) = make_float4(s[4], s[5], s[6], s[7]);
}

// pack hi16 of two fp32 (truncation; inputs >= 0) into one dword: lo<-a, hi<-b
__device__ __forceinline__ uint32_t pack_trunc2(float a, float b) {
    return __builtin_amdgcn_perm(__float_as_uint(b), __float_as_uint(a), 0x07060302u);
}

// ---------------------------------------------------------------------------
// GEMM: C[m][n] = sum_k A[m][k]*W[k][n] + bias[n]
// mode 0: out[((b*16+h)*2048+s)*64+hd]        (per-head [B,H,S,64])
// mode 1: out[m*1024+n]                        (row-major)
// mode 2: out[((b*16+h)*64+hd)*2048+s]         (per-head TRANSPOSED [B,H,64,S])
// ---------------------------------------------------------------------------
#define GT_M 128
#define GT_N 128
#define GT_K 16

template <typename TA, typename TO>
__global__ __launch_bounds__(256, 2)
void gemm_kernel(const TA *__restrict__ A,
                 const float *__restrict__ W,
                 const float *__restrict__ bias,
                 TO *__restrict__ out,
                 int mode)
{
    __shared__ float Ast[GT_K][GT_M + 4];
    __shared__ float Bs[GT_K][GT_N + 4];

    const int t = threadIdx.x;
    const int tx = t & 15;
    const int ty = t >> 4;
    const int m0 = blockIdx.y * GT_M;
    const int n0 = blockIdx.x * GT_N;

    float acc[8][8];
#pragma unroll
    for (int i = 0; i < 8; i++)
#pragma unroll
        for (int j = 0; j < 8; j++) acc[i][j] = 0.f;

    const int ar = t >> 1;
    const int ah = t & 1;
    const int bk = t >> 4;
    const int bp = t & 15;

    for (int k0 = 0; k0 < D_MODEL; k0 += GT_K) {
        float af[8], bf[8];
        load8(A + (size_t)(m0 + ar) * D_MODEL + k0 + ah * 8, af);
        load8(W + (size_t)(k0 + bk) * D_MODEL + n0 + bp * 8, bf);
#pragma unroll
        for (int i = 0; i < 8; i++) Ast[ah * 8 + i][ar] = af[i];
        *(float4 *)&Bs[bk][bp * 8 + 0] = make_float4(bf[0], bf[1], bf[2], bf[3]);
        *(float4 *)&Bs[bk][bp * 8 + 4] = make_float4(bf[4], bf[5], bf[6], bf[7]);
        __syncthreads();

#pragma unroll
        for (int kk = 0; kk < GT_K; kk++) {
            float a[8], b[8];
            *(float4 *)&a[0] = *(const float4 *)&Ast[kk][ty * 8];
            *(float4 *)&a[4] = *(const float4 *)&Ast[kk][ty * 8 + 4];
            *(float4 *)&b[0] = *(const float4 *)&Bs[kk][tx * 8];
            *(float4 *)&b[4] = *(const float4 *)&Bs[kk][tx * 8 + 4];
#pragma unroll
            for (int i = 0; i < 8; i++)
#pragma unroll
                for (int j = 0; j < 8; j++)
                    acc[i][j] = fmaf(a[i], b[j], acc[i][j]);
        }
        __syncthreads();
    }

    float bi[8];
    load8(bias + n0 + tx * 8, bi);

    const int ncol0 = n0 + tx * 8;
    if (mode == 2) {
        // transposed per-head write: pack along m (seq)
        const int m_base = m0 + ty * 8;
        const int b = m_base >> 11;
        const int s0 = m_base & 2047;
#pragma unroll
        for (int j = 0; j < 8; j++) {
            const int col = ncol0 + j;
            const int hh = col >> 6;
            const int hd = col & 63;
            float cv[8];
#pragma unroll
            for (int i = 0; i < 8; i++) cv[i] = acc[i][j] + bi[j];
            const size_t idx = ((size_t)(b * N_HEAD + hh) * HEAD_DIM + hd) * SEQ + s0;
            store8(out + idx, cv);
        }
    } else {
#pragma unroll
        for (int i = 0; i < 8; i++) {
            const int m = m0 + ty * 8 + i;
            float cv[8];
#pragma unroll
            for (int j = 0; j < 8; j++) cv[j] = acc[i][j] + bi[j];
            size_t idx;
            if (mode == 0) {
                const int b = m >> 11;
                const int s = m & 2047;
                const int hh = ncol0 >> 6;
                const int hd = ncol0 & 63;
                idx = ((size_t)(b * N_HEAD + hh) * SEQ + s) * HEAD_DIM + hd;
            } else {
                idx = (size_t)m * D_MODEL + ncol0;
            }
            store8(out + idx, cv);
        }
    }
}

// ---------------------------------------------------------------------------
// MFMA flash attention, causal, scale 1/32.
// Q,K: bf16 [B,H,S,64]; V: bf16 [B,H,64,S] (pre-transposed by mode-2 GEMM).
// AO: bf16 [B,S,1024].
// WG = 4 waves; wave w owns 16 queries (q0+16w..+15). K-tiles of 64 keys.
// MFMA 16x16x32 bf16. Fragment layouts (guide §3, m89/m120-verified):
//   A: m=lane&15, k=quad*8+j;  B: n=lane&15, k=quad*8+j;
//   C/D: col=lane&15, row=quad*4+reg.
// LDS K/V tiles XOR-swizzled on 8-elem groups: phys_g = g ^ (row&7) -> b128
// reads/writes at bank floor. P round-trips wave-private LDS (fp32, stride 68).
// ---------------------------------------------------------------------------
__device__ __forceinline__ int sw_off(int row, int gl) {
    return row * 64 + ((gl ^ (row & 7)) << 3);
}

__global__ __launch_bounds__(256, 2)
void attn_kernel(const unsigned short *__restrict__ Qg,
                 const unsigned short *__restrict__ Kg,
                 const unsigned short *__restrict__ VTg,
                 unsigned short *__restrict__ AO)
{
    __shared__ __align__(16) unsigned short Kt[64 * 64];
    __shared__ __align__(16) unsigned short Vt[64 * 64];
    __shared__ __align__(16) float SP[4][16 * 68]; // per-wave P buffer

    const int qb = blockIdx.x;  // 0..31
    const int h = blockIdx.y;
    const int b = blockIdx.z;
    const int t = threadIdx.x;
    const int wave = t >> 6;
    const int lane = t & 63;
    const int n = lane & 15;     // col index within MFMA tile
    const int quad = lane >> 4;  // 0..3
    const size_t head_off = (size_t)(b * N_HEAD + h) * SEQ * HEAD_DIM;

    const int q0 = qb * 64;
    const int qrow0 = q0 + wave * 16; // this wave's first query

    // --- Q A-fragments, straight from global (once) ---
    short8v qf[2];
#pragma unroll
    for (int kk = 0; kk < 2; kk++) {
        const unsigned short *qp =
            Qg + head_off + (size_t)(qrow0 + n) * HEAD_DIM + kk * 32 + quad * 8;
        qf[kk] = *(const short8v *)qp;
    }

    // online softmax state (per reg = per query row) + O accumulator
    float m_i[4], l_i[4];
    f32x4 Oacc[4]; // [dim-tile dt] C-layout
#pragma unroll
    for (int r = 0; r < 4; r++) {
        m_i[r] = -INFINITY;
        l_i[r] = 0.f;
        Oacc[r] = (f32x4){0.f, 0.f, 0.f, 0.f};
    }

    float *SPw = &SP[wave][0];
    const int r0 = t >> 3; // staging row 0..31
    const int g = t & 7;   // staging 8-elem group

    for (int kb = 0; kb <= qb; ++kb) {
        __syncthreads(); // previous tile fully consumed
        // --- stage K (keys x dims) and V^T (dims x keys), swizzled ---
#pragma unroll
        for (int i = 0; i < 2; i++) {
            const int r = r0 + 32 * i;
            U4 kv = *(const U4 *)(Kg + head_off + (size_t)(kb * 64 + r) * HEAD_DIM + g * 8);
            *(U4 *)&Kt[sw_off(r, g)] = kv;
            U4 vv = *(const U4 *)(VTg + head_off + (size_t)r * SEQ + kb * 64 + g * 8);
            *(U4 *)&Vt[sw_off(r, g)] = vv;
        }
        __syncthreads();

        // --- S = Q @ K^T (4 n-tiles x 2 k-chunks) ---
        f32x4 sc[4];
#pragma unroll
        for (int nt = 0; nt < 4; nt++) {
            short8v kf0 = *(const short8v *)&Kt[sw_off(nt * 16 + n, 0 * 4 + quad)];
            short8v kf1 = *(const short8v *)&Kt[sw_off(nt * 16 + n, 1 * 4 + quad)];
            f32x4 s = {0.f, 0.f, 0.f, 0.f};
            s = __builtin_amdgcn_mfma_f32_16x16x32_bf16(qf[0], kf0, s, 0, 0, 0);
            s = __builtin_amdgcn_mfma_f32_16x16x32_bf16(qf[1], kf1, s, 0, 0, 0);
            sc[nt] = s;
        }

        // --- scale + causal mask ---
        const bool diag = (kb == qb);
#pragma unroll
        for (int nt = 0; nt < 4; nt++) {
            const int kg = kb * 64 + nt * 16 + n;
#pragma unroll
            for (int r = 0; r < 4; r++) {
                float sv = sc[nt][r] * 0.03125f;
                if (diag && kg > qrow0 + quad * 4 + r) sv = -INFINITY;
                sc[nt][r] = sv;
            }
        }

        // --- online softmax (row stats across 16 lanes of this quad) ---
        float alpha[4];
#pragma unroll
        for (int r = 0; r < 4; r++) {
            float mx = fmaxf(fmaxf(sc[0][r], sc[1][r]), fmaxf(sc[2][r], sc[3][r]));
#pragma unroll
            for (int off = 8; off >= 1; off >>= 1)
                mx = fmaxf(mx, __shfl_xor(mx, off, 64));
            const float mnew = fmaxf(m_i[r], mx);
            alpha[r] = __expf(m_i[r] - mnew);
            m_i[r] = mnew;
#pragma unroll
            for (int nt = 0; nt < 4; nt++)
                sc[nt][r] = __expf(sc[nt][r] - mnew);
            float rs = sc[0][r] + sc[1][r] + sc[2][r] + sc[3][r];
#pragma unroll
            for (int off = 8; off >= 1; off >>= 1)
                rs += __shfl_xor(rs, off, 64);
            l_i[r] = l_i[r] * alpha[r] + rs;
        }
#pragma unroll
        for (int dt = 0; dt < 4; dt++)
#pragma unroll
            for (int r = 0; r < 4; r++)
                Oacc[dt][r] *= alpha[r];

        // --- P: C-layout -> A-layout via wave-private LDS (fp32) ---
#pragma unroll
        for (int nt = 0; nt < 4; nt++)
#pragma unroll
            for (int r = 0; r < 4; r++)
                SPw[(quad * 4 + r) * 68 + nt * 16 + n] = sc[nt][r];

        short8v pf[2];
#pragma unroll
        for (int c = 0; c < 2; c++) {
            const float *pp = &SPw[n * 68 + c * 32 + quad * 8];
            float4 lo = *(const float4 *)pp;
            float4 hi = *(const float4 *)(pp + 4);
            union { uint32_t u[4]; short8v s; } cv;
            cv.u[0] = pack_trunc2(lo.x, lo.y);
            cv.u[1] = pack_trunc2(lo.z, lo.w);
            cv.u[2] = pack_trunc2(hi.x, hi.y);
            cv.u[3] = pack_trunc2(hi.z, hi.w);
            pf[c] = cv.s;
        }

        // --- O += P @ V ---
#pragma unroll
        for (int c = 0; c < 2; c++) {
#pragma unroll
            for (int dt = 0; dt < 4; dt++) {
                short8v vf = *(const short8v *)&Vt[sw_off(dt * 16 + n, c * 4 + quad)];
                Oacc[dt] = __builtin_amdgcn_mfma_f32_16x16x32_bf16(pf[c], vf, Oacc[dt], 0, 0, 0);
            }
        }
    }

    // --- epilogue: AO[b][s][h*64 + dim] = O / l ---
    float linv[4];
#pragma unroll
    for (int r = 0; r < 4; r++) linv[r] = 1.f / l_i[r];
#pragma unroll
    for (int r = 0; r < 4; r++) {
        const int srow = qrow0 + quad * 4 + r;
        const size_t base = ((size_t)b * SEQ + srow) * D_MODEL + h * HEAD_DIM;
#pragma unroll
        for (int dt = 0; dt < 4; dt++)
            AO[base + dt * 16 + n] = f2bf(Oacc[dt][r] * linv[r]);
    }
}

// ---------------------------------------------------------------------------
extern "C" void kernel_launch(void *const *d_in, const int *in_sizes, int n_in,
                              void *d_out, int out_size, void *d_ws, size_t ws_size,
                              hipStream_t stream)
{
    const float *q  = (const float *)d_in[0];
    const float *k  = (const float *)d_in[1];
    const float *v  = (const float *)d_in[2];
    const float *Wq = (const float *)d_in[3];
    const float *bq = (const float *)d_in[4];
    const float *Wk = (const float *)d_in[5];
    const float *bk = (const float *)d_in[6];
    const float *Wv = (const float *)d_in[7];
    const float *bv = (const float *)d_in[8];
    const float *Wo = (const float *)d_in[9];
    const float *bo = (const float *)d_in[10];
    float *out = (float *)d_out;

    const size_t TENS = (size_t)M_ROWS * D_MODEL;
    unsigned short *wsq  = (unsigned short *)d_ws;   // [B,H,S,64]
    unsigned short *wsk  = wsq + TENS;               // [B,H,S,64]
    unsigned short *wsv  = wsk + TENS;               // [B,H,64,S] transposed
    unsigned short *wsao = wsv + TENS;               // [B,S,1024]

    dim3 gblk(256);
    dim3 ggrid(D_MODEL / GT_N, M_ROWS / GT_M);

    gemm_kernel<float, unsigned short><<<ggrid, gblk, 0, stream>>>(q, Wq, bq, wsq, 0);
    gemm_kernel<float, unsigned short><<<ggrid, gblk, 0, stream>>>(k, Wk, bk, wsk, 0);
    gemm_kernel<float, unsigned short><<<ggrid, gblk, 0, stream>>>(v, Wv, bv, wsv, 2);

    attn_kernel<<<dim3(SEQ / 64, N_HEAD, BATCH), 256, 0, stream>>>(wsq, wsk, wsv, wsao);

    gemm_kernel<unsigned short, float><<<ggrid, gblk, 0, stream>>>(wsao, Wo, bo, out, 1);
}

// Round 5
// 536.577 us; speedup vs baseline: 6.7628x; 2.2642x over previous
//
#include <hip/hip_runtime.h>
#include <hip/hip_bf16.h>
#include <cstdint>
#include <cstddef>

#define D_MODEL 1024
#define N_HEAD 16
#define HEAD_DIM 64
#define BATCH 4
#define SEQ 2048
#define M_ROWS (BATCH * SEQ) // 8192

typedef __attribute__((ext_vector_type(8))) short short8v; // 8 bf16 (4 VGPRs)
typedef __attribute__((ext_vector_type(4))) float f32x4;   // MFMA C/D

// ---------- bf16 helpers ----------
__device__ __forceinline__ unsigned short f2bf(float f) { // RNE
    union { uint32_t i; float f; } c;
    c.f = f;
    uint32_t r = c.i + 0x7FFFu + ((c.i >> 16) & 1u);
    return (unsigned short)(r >> 16);
}
__device__ __forceinline__ unsigned short trunc_bf(float f) { // exact on bf16-grid data
    return (unsigned short)(__float_as_uint(f) >> 16);
}
// pack hi16 of two fp32 into one dword: lo<-a, hi<-b (truncation)
__device__ __forceinline__ uint32_t pack_trunc2(float a, float b) {
    return __builtin_amdgcn_perm(__float_as_uint(b), __float_as_uint(a), 0x07060302u);
}

struct __align__(16) U4 { uint32_t x, y, z, w; };

// swizzled LDS offset (elements): row*64 + (8-elem group XOR low row bits)*8
__device__ __forceinline__ int sw_off(int row, int gl) {
    return row * 64 + ((gl ^ (row & 7)) << 3);
}

// ---------------------------------------------------------------------------
// Weight transpose+convert: W[1024][1024] fp32 row-major -> Wt[n][k] bf16.
// ---------------------------------------------------------------------------
__global__ __launch_bounds__(256)
void wtrans_kernel(const float *__restrict__ W, unsigned short *__restrict__ Wt)
{
    __shared__ float tile[32][33];
    const int t = threadIdx.x;
    const int tx = t & 31, ty = t >> 5; // ty 0..7
    const int bk = blockIdx.y * 32, bn = blockIdx.x * 32;
#pragma unroll
    for (int i = 0; i < 4; i++)
        tile[ty + 8 * i][tx] = W[(size_t)(bk + ty + 8 * i) * D_MODEL + bn + tx];
    __syncthreads();
#pragma unroll
    for (int i = 0; i < 4; i++)
        Wt[(size_t)(bn + ty + 8 * i) * D_MODEL + bk + tx] = trunc_bf(tile[tx][ty + 8 * i]);
}

// ---------------------------------------------------------------------------
// MFMA GEMM: C[m][n] = sum_k A[m][k]*W[k][n] + bias[n]
// A: [8192][1024], TA = float (converted in staging) or ushort (bf16)
// Wt: bf16 [n][k] (pre-transposed); bias fp32.
// MODE 1: bf16 row-major out[m*1024+n]
// MODE 2: bf16 transposed-per-head out[((b*16+h)*64+hd)*2048+s]
// MODE 3: fp32 row-major
// 256 thr, 128x128 tile, BK=64, wave w -> 64x64 quadrant (wm=w>>1, wn=w&1).
// ---------------------------------------------------------------------------
template <typename TA, int MODE, typename TO>
__global__ __launch_bounds__(256, 2)
void mgemm_kernel(const TA *__restrict__ A,
                  const unsigned short *__restrict__ Wt,
                  const float *__restrict__ bias,
                  TO *__restrict__ out)
{
    __shared__ __align__(16) unsigned short At[128 * 64];
    __shared__ __align__(16) unsigned short Bt[128 * 64];

    const int t = threadIdx.x;
    const int wave = t >> 6;
    const int lane = t & 63;
    const int n_ = lane & 15;
    const int quad = lane >> 4;
    const int wm = wave >> 1, wn = wave & 1;
    const int m0 = blockIdx.y * 128;
    const int n0 = blockIdx.x * 128;

    f32x4 acc[4][4];
#pragma unroll
    for (int i = 0; i < 4; i++)
#pragma unroll
        for (int j = 0; j < 4; j++) acc[i][j] = (f32x4){0.f, 0.f, 0.f, 0.f};

    const int srow = t >> 3; // staging row 0..31 (+32*i)
    const int sg = t & 7;    // staging 8-elem group

    for (int k0 = 0; k0 < D_MODEL; k0 += 64) {
        __syncthreads();
        // ---- stage A (fp32->bf16 cvt, or bf16 copy) ----
#pragma unroll
        for (int i = 0; i < 4; i++) {
            const int r = srow + 32 * i;
            if constexpr (sizeof(TA) == 4) {
                const float *p = (const float *)A + (size_t)(m0 + r) * D_MODEL + k0 + sg * 8;
                float4 lo = *(const float4 *)p;
                float4 hi = *(const float4 *)(p + 4);
                U4 pk;
                pk.x = pack_trunc2(lo.x, lo.y);
                pk.y = pack_trunc2(lo.z, lo.w);
                pk.z = pack_trunc2(hi.x, hi.y);
                pk.w = pack_trunc2(hi.z, hi.w);
                *(U4 *)&At[sw_off(r, sg)] = pk;
            } else {
                const unsigned short *p =
                    (const unsigned short *)A + (size_t)(m0 + r) * D_MODEL + k0 + sg * 8;
                *(U4 *)&At[sw_off(r, sg)] = *(const U4 *)p;
            }
        }
        // ---- stage B from Wt[n][k] (bf16) ----
#pragma unroll
        for (int i = 0; i < 4; i++) {
            const int r = srow + 32 * i;
            const unsigned short *p = Wt + (size_t)(n0 + r) * D_MODEL + k0 + sg * 8;
            *(U4 *)&Bt[sw_off(r, sg)] = *(const U4 *)p;
        }
        __syncthreads();

        // ---- compute: 2 k-chunks x (4 mt x 4 nt) ----
#pragma unroll
        for (int c = 0; c < 2; c++) {
            short8v af[4], bf[4];
#pragma unroll
            for (int mt = 0; mt < 4; mt++)
                af[mt] = *(const short8v *)&At[sw_off(wm * 64 + mt * 16 + n_, c * 4 + quad)];
#pragma unroll
            for (int nt = 0; nt < 4; nt++)
                bf[nt] = *(const short8v *)&Bt[sw_off(wn * 64 + nt * 16 + n_, c * 4 + quad)];
#pragma unroll
            for (int mt = 0; mt < 4; mt++)
#pragma unroll
                for (int nt = 0; nt < 4; nt++)
                    acc[mt][nt] =
                        __builtin_amdgcn_mfma_f32_16x16x32_bf16(af[mt], bf[nt], acc[mt][nt], 0, 0, 0);
        }
    }

    // ---- epilogue ----
    float bi[4];
#pragma unroll
    for (int nt = 0; nt < 4; nt++) bi[nt] = bias[n0 + wn * 64 + nt * 16 + n_];

#pragma unroll
    for (int mt = 0; mt < 4; mt++) {
#pragma unroll
        for (int reg = 0; reg < 4; reg++) {
            const int m = m0 + wm * 64 + mt * 16 + quad * 4 + reg;
#pragma unroll
            for (int nt = 0; nt < 4; nt++) {
                const int col = n0 + wn * 64 + nt * 16 + n_;
                const float v = acc[mt][nt][reg] + bi[nt];
                if constexpr (MODE == 1) {
                    ((unsigned short *)out)[(size_t)m * D_MODEL + col] = f2bf(v);
                } else if constexpr (MODE == 2) {
                    const size_t idx = ((size_t)(m >> 11) * D_MODEL + col) * SEQ + (m & 2047);
                    ((unsigned short *)out)[idx] = f2bf(v);
                } else {
                    ((float *)out)[(size_t)m * D_MODEL + col] = v;
                }
            }
        }
    }
}

// ---------------------------------------------------------------------------
// MFMA flash attention (R4-verified), causal, scale 1/32.
// Q,K: bf16 ROW-MAJOR [B*S][1024] (head offset h*64 applied here).
// V: bf16 [B,H,64,S] (pre-transposed). AO: bf16 [B,S,1024] (may alias Qg:
// each block reads exactly the Q region it later writes as AO).
// ---------------------------------------------------------------------------
__global__ __launch_bounds__(256, 2)
void attn_kernel(const unsigned short *Qg,
                 const unsigned short *__restrict__ Kg,
                 const unsigned short *__restrict__ VTg,
                 unsigned short *AO)
{
    __shared__ __align__(16) unsigned short Kt[64 * 64];
    __shared__ __align__(16) unsigned short Vt[64 * 64];
    __shared__ __align__(16) float SP[4][16 * 68];

    const int qb = blockIdx.x;
    const int h = blockIdx.y;
    const int b = blockIdx.z;
    const int t = threadIdx.x;
    const int wave = t >> 6;
    const int lane = t & 63;
    const int n = lane & 15;
    const int quad = lane >> 4;

    const size_t row_base = (size_t)b * SEQ * D_MODEL + h * HEAD_DIM; // row-major Q/K base
    const size_t vhead = (size_t)(b * N_HEAD + h) * HEAD_DIM * SEQ;   // V^T base

    const int qrow0 = qb * 64 + wave * 16;

    short8v qf[2];
#pragma unroll
    for (int kk = 0; kk < 2; kk++)
        qf[kk] = *(const short8v *)(Qg + row_base + (size_t)(qrow0 + n) * D_MODEL + kk * 32 + quad * 8);

    float m_i[4], l_i[4];
    f32x4 Oacc[4];
#pragma unroll
    for (int r = 0; r < 4; r++) {
        m_i[r] = -INFINITY;
        l_i[r] = 0.f;
        Oacc[r] = (f32x4){0.f, 0.f, 0.f, 0.f};
    }

    float *SPw = &SP[wave][0];
    const int r0 = t >> 3;
    const int g = t & 7;

    for (int kb = 0; kb <= qb; ++kb) {
        __syncthreads();
#pragma unroll
        for (int i = 0; i < 2; i++) {
            const int r = r0 + 32 * i;
            U4 kv = *(const U4 *)(Kg + row_base + (size_t)(kb * 64 + r) * D_MODEL + g * 8);
            *(U4 *)&Kt[sw_off(r, g)] = kv;
            U4 vv = *(const U4 *)(VTg + vhead + (size_t)r * SEQ + kb * 64 + g * 8);
            *(U4 *)&Vt[sw_off(r, g)] = vv;
        }
        __syncthreads();

        f32x4 sc[4];
#pragma unroll
        for (int nt = 0; nt < 4; nt++) {
            short8v kf0 = *(const short8v *)&Kt[sw_off(nt * 16 + n, 0 * 4 + quad)];
            short8v kf1 = *(const short8v *)&Kt[sw_off(nt * 16 + n, 1 * 4 + quad)];
            f32x4 s = {0.f, 0.f, 0.f, 0.f};
            s = __builtin_amdgcn_mfma_f32_16x16x32_bf16(qf[0], kf0, s, 0, 0, 0);
            s = __builtin_amdgcn_mfma_f32_16x16x32_bf16(qf[1], kf1, s, 0, 0, 0);
            sc[nt] = s;
        }

        const bool diag = (kb == qb);
#pragma unroll
        for (int nt = 0; nt < 4; nt++) {
            const int kg = kb * 64 + nt * 16 + n;
#pragma unroll
            for (int r = 0; r < 4; r++) {
                float sv = sc[nt][r] * 0.03125f;
                if (diag && kg > qrow0 + quad * 4 + r) sv = -INFINITY;
                sc[nt][r] = sv;
            }
        }

        float alpha[4];
#pragma unroll
        for (int r = 0; r < 4; r++) {
            float mx = fmaxf(fmaxf(sc[0][r], sc[1][r]), fmaxf(sc[2][r], sc[3][r]));
#pragma unroll
            for (int off = 8; off >= 1; off >>= 1)
                mx = fmaxf(mx, __shfl_xor(mx, off, 64));
            const float mnew = fmaxf(m_i[r], mx);
            alpha[r] = __expf(m_i[r] - mnew);
            m_i[r] = mnew;
#pragma unroll
            for (int nt = 0; nt < 4; nt++)
                sc[nt][r] = __expf(sc[nt][r] - mnew);
            float rs = sc[0][r] + sc[1][r] + sc[2][r] + sc[3][r];
#pragma unroll
            for (int off = 8; off >= 1; off >>= 1)
                rs += __shfl_xor(rs, off, 64);
            l_i[r] = l_i[r] * alpha[r] + rs;
        }
#pragma unroll
        for (int dt = 0; dt < 4; dt++)
#pragma unroll
            for (int r = 0; r < 4; r++)
                Oacc[dt][r] *= alpha[r];

#pragma unroll
        for (int nt = 0; nt < 4; nt++)
#pragma unroll
            for (int r = 0; r < 4; r++)
                SPw[(quad * 4 + r) * 68 + nt * 16 + n] = sc[nt][r];

        short8v pf[2];
#pragma unroll
        for (int c = 0; c < 2; c++) {
            const float *pp = &SPw[n * 68 + c * 32 + quad * 8];
            float4 lo = *(const float4 *)pp;
            float4 hi = *(const float4 *)(pp + 4);
            union { uint32_t u[4]; short8v s; } cv;
            cv.u[0] = pack_trunc2(lo.x, lo.y);
            cv.u[1] = pack_trunc2(lo.z, lo.w);
            cv.u[2] = pack_trunc2(hi.x, hi.y);
            cv.u[3] = pack_trunc2(hi.z, hi.w);
            pf[c] = cv.s;
        }

#pragma unroll
        for (int c = 0; c < 2; c++)
#pragma unroll
            for (int dt = 0; dt < 4; dt++) {
                short8v vf = *(const short8v *)&Vt[sw_off(dt * 16 + n, c * 4 + quad)];
                Oacc[dt] = __builtin_amdgcn_mfma_f32_16x16x32_bf16(pf[c], vf, Oacc[dt], 0, 0, 0);
            }
    }

    float linv[4];
#pragma unroll
    for (int r = 0; r < 4; r++) linv[r] = 1.f / l_i[r];
#pragma unroll
    for (int r = 0; r < 4; r++) {
        const int srow = qrow0 + quad * 4 + r;
        const size_t base = ((size_t)b * SEQ + srow) * D_MODEL + h * HEAD_DIM;
#pragma unroll
        for (int dt = 0; dt < 4; dt++)
            AO[base + dt * 16 + n] = f2bf(Oacc[dt][r] * linv[r]);
    }
}

// ---------------------------------------------------------------------------
extern "C" void kernel_launch(void *const *d_in, const int *in_sizes, int n_in,
                              void *d_out, int out_size, void *d_ws, size_t ws_size,
                              hipStream_t stream)
{
    const float *q  = (const float *)d_in[0];
    const float *k  = (const float *)d_in[1];
    const float *v  = (const float *)d_in[2];
    const float *Wq = (const float *)d_in[3];
    const float *bq = (const float *)d_in[4];
    const float *Wk = (const float *)d_in[5];
    const float *bk = (const float *)d_in[6];
    const float *Wv = (const float *)d_in[7];
    const float *bv = (const float *)d_in[8];
    const float *Wo = (const float *)d_in[9];
    const float *bo = (const float *)d_in[10];
    float *out = (float *)d_out;

    // ws: qbuf(=AO alias) + kbuf + vtbuf (bf16, 16.8 MB each) + wt (2.1 MB) = 52.4 MB
    const size_t TENS = (size_t)M_ROWS * D_MODEL;
    unsigned short *qbuf = (unsigned short *)d_ws;   // [8192][1024] bf16; AO aliases this
    unsigned short *kbuf = qbuf + TENS;              // [8192][1024] bf16
    unsigned short *vtbuf = kbuf + TENS;             // [B,H,64,S] bf16
    unsigned short *wt = vtbuf + TENS;               // [1024][1024] bf16 (transposed W)

    dim3 wgrid(32, 32);
    dim3 ggrid(D_MODEL / 128, M_ROWS / 128); // (8, 64)

    wtrans_kernel<<<wgrid, 256, 0, stream>>>(Wq, wt);
    mgemm_kernel<float, 1, unsigned short><<<ggrid, 256, 0, stream>>>(q, wt, bq, qbuf);
    wtrans_kernel<<<wgrid, 256, 0, stream>>>(Wk, wt);
    mgemm_kernel<float, 1, unsigned short><<<ggrid, 256, 0, stream>>>(k, wt, bk, kbuf);
    wtrans_kernel<<<wgrid, 256, 0, stream>>>(Wv, wt);
    mgemm_kernel<float, 2, unsigned short><<<ggrid, 256, 0, stream>>>(v, wt, bv, vtbuf);

    attn_kernel<<<dim3(SEQ / 64, N_HEAD, BATCH), 256, 0, stream>>>(qbuf, kbuf, vtbuf, qbuf);

    wtrans_kernel<<<wgrid, 256, 0, stream>>>(Wo, wt);
    mgemm_kernel<unsigned short, 3, float><<<ggrid, 256, 0, stream>>>(qbuf, wt, bo, out);
}